// Round 1
// 265.023 us; speedup vs baseline: 1.0085x; 1.0085x over previous
//
#include <hip/hip_runtime.h>

// (B,T,S,D) = (4,2048,4,1024); all tensors float32.
// Restructure vs previous version (95us/dispatch, 2.3 TB/s, VGPR=40):
//  - aH/hp coefficients -> SGPRs via readfirstlane (wave-uniform; frees 20 VGPRs)
//  - combined bias -> LDS (16 KB/block; frees 16 VGPRs; contiguous ds_read_b128)
//  - depth-2 software pipeline: tile t+1 loads issue BEFORE tile t stores, so
//    counted vmcnt waits for loads never drain through older nontemporal
//    stores (vmcnt retires in order; nt stores ack at HBM latency).
//  - tile-0 loads issued before the Sinkhorn prologue to hide it.
constexpr int Bc = 4;
constexpr int Tc = 2048;
constexpr int Sc = 4;
constexpr int Dc = 1024;
constexpr int BT = Bc * Tc;                 // 8192
constexpr int SD = Sc * Dc;                 // 4096
constexpr int SINKHORN_ITERS = 20;
constexpr int NBLK = 2048;                  // exact machine fill: 8 blocks/CU

typedef float vfloat4 __attribute__((ext_vector_type(4)));

__device__ __forceinline__ float uniform_f(float v) {
    return __uint_as_float(__builtin_amdgcn_readfirstlane(__float_as_uint(v)));
}

__global__ __launch_bounds__(256) void fused_kernel(
        const float* __restrict__ x,
        const float* __restrict__ lo,
        const float* __restrict__ Hres,
        const float* __restrict__ Hpos,
        const float* __restrict__ alpha_res,
        const float* __restrict__ alpha_pos,
        const float* __restrict__ bias_res,
        const float* __restrict__ bias_pos,
        float* __restrict__ out) {
    __shared__ float s_aH[16];     // s_aH[r*4+s] = alpha_res * P[s][r]
    __shared__ float s_hp[4];      // alpha_pos * H_pos[r]
    __shared__ vfloat4 s_cb[4 * 256];  // [r][tid]: bias_res+bias_pos, 16 KB

    const int tid = threadIdx.x;
    const int d0 = tid << 2;
    const int bt0 = blockIdx.x;

    // ---- issue tile-0 global loads first (hide prologue under HBM latency) ----
    const float* xp0 = x + bt0 * SD + d0;
    vfloat4 a0 = *reinterpret_cast<const vfloat4*>(xp0);
    vfloat4 a1 = *reinterpret_cast<const vfloat4*>(xp0 + Dc);
    vfloat4 a2 = *reinterpret_cast<const vfloat4*>(xp0 + 2 * Dc);
    vfloat4 a3 = *reinterpret_cast<const vfloat4*>(xp0 + 3 * Dc);
    vfloat4 al = *reinterpret_cast<const vfloat4*>(lo + bt0 * Dc + d0);

    // ---- stage combined bias into LDS (L2-hot 16 KB arrays) ----
#pragma unroll
    for (int r = 0; r < 4; ++r) {
        const vfloat4 br = *reinterpret_cast<const vfloat4*>(bias_res + r * Dc + d0);
        const vfloat4 bp = *reinterpret_cast<const vfloat4*>(bias_pos + r * Dc + d0);
        s_cb[r * 256 + tid] = br + bp;
    }

    // ---- Sinkhorn on H (4x4), first 16 lanes of wave 0 ----
    if (tid < 16) {
        const int i = tid >> 2;     // row
        const int j = tid & 3;      // col
        const float h = Hres[i * 4 + j];
        float m = fmaxf(h, __shfl_xor(h, 1));
        m = fmaxf(m, __shfl_xor(m, 2));
        float P = __expf(h - m);
        for (int it = 0; it < SINKHORN_ITERS; ++it) {
            float s = P + __shfl_xor(P, 1);
            s += __shfl_xor(s, 2);
            P *= __builtin_amdgcn_rcpf(s + 1e-8f);   // ~1e-5 rel err, fine
            float c = P + __shfl_xor(P, 4);
            c += __shfl_xor(c, 8);
            P *= __builtin_amdgcn_rcpf(c + 1e-8f);
        }
        // einsum 'btsd,sr->btrd': out stream r contracts x stream s with P[s][r].
        s_aH[j * 4 + i] = alpha_res[0] * P;
        if (i == 0) s_hp[j] = alpha_pos[0] * Hpos[j];
    }
    __syncthreads();

    // ---- wave-uniform coefficients -> SGPRs (one SGPR operand per FMA is legal) ----
    float aH[4][4];
    float hp[4];
#pragma unroll
    for (int r = 0; r < 4; ++r) {
#pragma unroll
        for (int s = 0; s < 4; ++s) aH[r][s] = uniform_f(s_aH[r * 4 + s]);
        hp[r] = uniform_f(s_hp[r]);
    }

    // ---- helpers ----
    auto load_tile = [&](int bt, vfloat4& x0, vfloat4& x1, vfloat4& x2,
                         vfloat4& x3, vfloat4& lv) {
        const float* xp = x + bt * SD + d0;
        x0 = *reinterpret_cast<const vfloat4*>(xp);
        x1 = *reinterpret_cast<const vfloat4*>(xp + Dc);
        x2 = *reinterpret_cast<const vfloat4*>(xp + 2 * Dc);
        x3 = *reinterpret_cast<const vfloat4*>(xp + 3 * Dc);
        lv = *reinterpret_cast<const vfloat4*>(lo + bt * Dc + d0);
    };

    auto compute_store = [&](int bt, vfloat4 x0, vfloat4 x1, vfloat4 x2,
                             vfloat4 x3, vfloat4 lv) {
        float* op = out + bt * SD + d0;
        vfloat4 xs[4] = {x0, x1, x2, x3};   // static indexing only -> registers
#pragma unroll
        for (int r = 0; r < 4; ++r) {
            const vfloat4 cb = s_cb[r * 256 + tid];
            vfloat4 acc;
#pragma unroll
            for (int j = 0; j < 4; ++j)
                acc[j] = fmaf(lv[j], hp[r], xs[r][j] + cb[j]);
#pragma unroll
            for (int s = 0; s < 4; ++s)
#pragma unroll
                for (int j = 0; j < 4; ++j)
                    acc[j] = fmaf(xs[s][j], aH[r][s], acc[j]);
            __builtin_nontemporal_store(acc, reinterpret_cast<vfloat4*>(op + r * Dc));
        }
    };

    // ---- depth-2 pipelined walk over 4 bt-tiles ----
    vfloat4 b0, b1, b2, b3, bl;
    load_tile(bt0 + NBLK, b0, b1, b2, b3, bl);        // loads(t1) before stores(t0)
    compute_store(bt0, a0, a1, a2, a3, al);
    load_tile(bt0 + 2 * NBLK, a0, a1, a2, a3, al);    // loads(t2) before stores(t1)
    compute_store(bt0 + NBLK, b0, b1, b2, b3, bl);
    load_tile(bt0 + 3 * NBLK, b0, b1, b2, b3, bl);    // loads(t3) before stores(t2)
    compute_store(bt0 + 2 * NBLK, a0, a1, a2, a3, al);
    compute_store(bt0 + 3 * NBLK, b0, b1, b2, b3, bl);
}

extern "C" void kernel_launch(void* const* d_in, const int* in_sizes, int n_in,
                              void* d_out, int out_size, void* d_ws, size_t ws_size,
                              hipStream_t stream) {
    const float* x         = (const float*)d_in[0];
    const float* layer_out = (const float*)d_in[1];
    const float* H_res     = (const float*)d_in[2];
    const float* H_pos     = (const float*)d_in[3];
    const float* alpha_res = (const float*)d_in[4];
    const float* alpha_pos = (const float*)d_in[5];
    const float* bias_res  = (const float*)d_in[6];
    const float* bias_pos  = (const float*)d_in[7];
    float* out = (float*)d_out;

    fused_kernel<<<NBLK, 256, 0, stream>>>(x, layer_out, H_res, H_pos,
                                           alpha_res, alpha_pos,
                                           bias_res, bias_pos, out);
}

// Round 2
// 264.878 us; speedup vs baseline: 1.0090x; 1.0005x over previous
//
#include <hip/hip_runtime.h>

// (B,T,S,D) = (4,2048,4,1024); all tensors float32.
// Round-2 single-variable change vs Round-1: TEMPORAL stores (was nontemporal).
// Evidence: WRITE_SIZE/dur == 1.45 TB/s == whole-dispatch duration in R0 and R1;
// schedule changes (VGPR 40 vs 32) moved nothing -> write path is the cap.
// The 6.3 TB/s copy ubench sustains ~3.15 TB/s of TEMPORAL writes, 2x our nt rate.
constexpr int Bc = 4;
constexpr int Tc = 2048;
constexpr int Sc = 4;
constexpr int Dc = 1024;
constexpr int BT = Bc * Tc;                 // 8192
constexpr int SD = Sc * Dc;                 // 4096
constexpr int SINKHORN_ITERS = 20;
constexpr int NBLK = 2048;                  // 8 blocks/CU

typedef float vfloat4 __attribute__((ext_vector_type(4)));

__device__ __forceinline__ float uniform_f(float v) {
    return __uint_as_float(__builtin_amdgcn_readfirstlane(__float_as_uint(v)));
}

__global__ __launch_bounds__(256) void fused_kernel(
        const float* __restrict__ x,
        const float* __restrict__ lo,
        const float* __restrict__ Hres,
        const float* __restrict__ Hpos,
        const float* __restrict__ alpha_res,
        const float* __restrict__ alpha_pos,
        const float* __restrict__ bias_res,
        const float* __restrict__ bias_pos,
        float* __restrict__ out) {
    __shared__ float s_aH[16];     // s_aH[r*4+s] = alpha_res * P[s][r]
    __shared__ float s_hp[4];      // alpha_pos * H_pos[r]
    __shared__ vfloat4 s_cb[4 * 256];  // [r][tid]: bias_res+bias_pos, 16 KB

    const int tid = threadIdx.x;
    const int d0 = tid << 2;
    const int bt0 = blockIdx.x;

    // ---- issue tile-0 global loads first (hide prologue under HBM latency) ----
    const float* xp0 = x + bt0 * SD + d0;
    vfloat4 a0 = *reinterpret_cast<const vfloat4*>(xp0);
    vfloat4 a1 = *reinterpret_cast<const vfloat4*>(xp0 + Dc);
    vfloat4 a2 = *reinterpret_cast<const vfloat4*>(xp0 + 2 * Dc);
    vfloat4 a3 = *reinterpret_cast<const vfloat4*>(xp0 + 3 * Dc);
    vfloat4 al = *reinterpret_cast<const vfloat4*>(lo + bt0 * Dc + d0);

    // ---- stage combined bias into LDS (L2-hot 16 KB arrays) ----
#pragma unroll
    for (int r = 0; r < 4; ++r) {
        const vfloat4 br = *reinterpret_cast<const vfloat4*>(bias_res + r * Dc + d0);
        const vfloat4 bp = *reinterpret_cast<const vfloat4*>(bias_pos + r * Dc + d0);
        s_cb[r * 256 + tid] = br + bp;
    }

    // ---- Sinkhorn on H (4x4), first 16 lanes of wave 0 ----
    if (tid < 16) {
        const int i = tid >> 2;     // row
        const int j = tid & 3;      // col
        const float h = Hres[i * 4 + j];
        float m = fmaxf(h, __shfl_xor(h, 1));
        m = fmaxf(m, __shfl_xor(m, 2));
        float P = __expf(h - m);
        for (int it = 0; it < SINKHORN_ITERS; ++it) {
            float s = P + __shfl_xor(P, 1);
            s += __shfl_xor(s, 2);
            P *= __builtin_amdgcn_rcpf(s + 1e-8f);   // ~1e-5 rel err, fine
            float c = P + __shfl_xor(P, 4);
            c += __shfl_xor(c, 8);
            P *= __builtin_amdgcn_rcpf(c + 1e-8f);
        }
        // einsum 'btsd,sr->btrd': out stream r contracts x stream s with P[s][r].
        s_aH[j * 4 + i] = alpha_res[0] * P;
        if (i == 0) s_hp[j] = alpha_pos[0] * Hpos[j];
    }
    __syncthreads();

    // ---- wave-uniform coefficients -> SGPRs ----
    float aH[4][4];
    float hp[4];
#pragma unroll
    for (int r = 0; r < 4; ++r) {
#pragma unroll
        for (int s = 0; s < 4; ++s) aH[r][s] = uniform_f(s_aH[r * 4 + s]);
        hp[r] = uniform_f(s_hp[r]);
    }

    // ---- helpers ----
    auto load_tile = [&](int bt, vfloat4& x0, vfloat4& x1, vfloat4& x2,
                         vfloat4& x3, vfloat4& lv) {
        const float* xp = x + bt * SD + d0;
        x0 = *reinterpret_cast<const vfloat4*>(xp);
        x1 = *reinterpret_cast<const vfloat4*>(xp + Dc);
        x2 = *reinterpret_cast<const vfloat4*>(xp + 2 * Dc);
        x3 = *reinterpret_cast<const vfloat4*>(xp + 3 * Dc);
        lv = *reinterpret_cast<const vfloat4*>(lo + bt * Dc + d0);
    };

    auto compute_store = [&](int bt, vfloat4 x0, vfloat4 x1, vfloat4 x2,
                             vfloat4 x3, vfloat4 lv) {
        float* op = out + bt * SD + d0;
        vfloat4 xs[4] = {x0, x1, x2, x3};   // static indexing only -> registers
#pragma unroll
        for (int r = 0; r < 4; ++r) {
            const vfloat4 cb = s_cb[r * 256 + tid];
            vfloat4 acc;
#pragma unroll
            for (int j = 0; j < 4; ++j)
                acc[j] = fmaf(lv[j], hp[r], xs[r][j] + cb[j]);
#pragma unroll
            for (int s = 0; s < 4; ++s)
#pragma unroll
                for (int j = 0; j < 4; ++j)
                    acc[j] = fmaf(xs[s][j], aH[r][s], acc[j]);
            // TEMPORAL store (the single change): write-allocate L2, async writeback.
            *reinterpret_cast<vfloat4*>(op + r * Dc) = acc;
        }
    };

    // ---- depth-2 pipelined walk over 4 bt-tiles ----
    vfloat4 b0, b1, b2, b3, bl;
    load_tile(bt0 + NBLK, b0, b1, b2, b3, bl);
    compute_store(bt0, a0, a1, a2, a3, al);
    load_tile(bt0 + 2 * NBLK, a0, a1, a2, a3, al);
    compute_store(bt0 + NBLK, b0, b1, b2, b3, bl);
    load_tile(bt0 + 3 * NBLK, b0, b1, b2, b3, bl);
    compute_store(bt0 + 2 * NBLK, a0, a1, a2, a3, al);
    compute_store(bt0 + 3 * NBLK, b0, b1, b2, b3, bl);
}

extern "C" void kernel_launch(void* const* d_in, const int* in_sizes, int n_in,
                              void* d_out, int out_size, void* d_ws, size_t ws_size,
                              hipStream_t stream) {
    const float* x         = (const float*)d_in[0];
    const float* layer_out = (const float*)d_in[1];
    const float* H_res     = (const float*)d_in[2];
    const float* H_pos     = (const float*)d_in[3];
    const float* alpha_res = (const float*)d_in[4];
    const float* alpha_pos = (const float*)d_in[5];
    const float* bias_res  = (const float*)d_in[6];
    const float* bias_pos  = (const float*)d_in[7];
    float* out = (float*)d_out;

    fused_kernel<<<NBLK, 256, 0, stream>>>(x, layer_out, H_res, H_pos,
                                           alpha_res, alpha_pos,
                                           bias_res, bias_pos, out);
}